// Round 1
// baseline (396.403 us; speedup 1.0000x reference)
//
#include <hip/hip_runtime.h>
#include <math.h>

#define DD 8
#define BB 4096
#define VV 1024
#define K_SEL 102

__device__ __forceinline__ unsigned f2key(float f) {
    unsigned u = __float_as_uint(f);
    return u ^ ((u & 0x80000000u) ? 0xFFFFFFFFu : 0x80000000u);
}
__device__ __forceinline__ float key2f(unsigned k) {
    unsigned u = (k & 0x80000000u) ? (k ^ 0x80000000u) : ~k;
    return __uint_as_float(u);
}

// One block per (d,b) row. 256 threads, 4 elements each.
__global__ __launch_bounds__(256) void decode_row_kernel(
    const float* __restrict__ logits,
    const float* __restrict__ unoise,
    const int* __restrict__ curvals,
    float* __restrict__ probs_out,   // [D*B*V], d_out + B*D
    int* __restrict__ samples)       // [D*B] in workspace
{
    const int row = blockIdx.x;              // row = d*B + b
    const int tid = threadIdx.x;
    const float* lrow = logits + (size_t)row * VV;
    const float* urow = unoise + (size_t)row * VV;
    const int cv = curvals[row];

    const float NEG = -INFINITY;

    // ---- load + mask ----
    float x[4];
    unsigned keys[4];
#pragma unroll
    for (int i = 0; i < 4; i++) {
        int v = tid + i * 256;
        float f = lrow[v];
        if (v == 0 || v < cv) f = NEG;
        x[i] = f;
        keys[i] = f2key(f);
    }

    __shared__ unsigned hist[256];
    __shared__ unsigned suf[256];
    __shared__ unsigned s_bin, s_k;
    __shared__ float redv[256];
    __shared__ int   redi[256];

    // ---- exact radix select: key of the K_SEL-th largest value ----
    unsigned prefix = 0;
    unsigned pmask = 0;
    unsigned kk = K_SEL;
#pragma unroll
    for (int pass = 0; pass < 4; pass++) {
        const int shift = 24 - 8 * pass;
        hist[tid] = 0;
        __syncthreads();
#pragma unroll
        for (int i = 0; i < 4; i++) {
            if ((keys[i] & pmask) == prefix)
                atomicAdd(&hist[(keys[i] >> shift) & 0xFFu], 1u);
        }
        __syncthreads();
        // inclusive suffix sum: suf[t] = sum_{b>=t} hist[b]
        suf[tid] = hist[tid];
        __syncthreads();
        for (int off = 1; off < 256; off <<= 1) {
            unsigned val = suf[tid];
            unsigned add = (tid + off < 256) ? suf[tid + off] : 0u;
            __syncthreads();
            suf[tid] = val + add;
            __syncthreads();
        }
        unsigned gt = suf[tid] - hist[tid];   // count in bins strictly greater
        if (gt < kk && suf[tid] >= kk) {
            s_bin = (unsigned)tid;
            s_k = kk - gt;
        }
        __syncthreads();
        prefix |= (s_bin << shift);
        pmask |= (0xFFu << shift);
        kk = s_k;
        __syncthreads();
    }
    const float kth = key2f(prefix);

    // ---- top-k filter ----
#pragma unroll
    for (int i = 0; i < 4; i++)
        if (x[i] < kth) x[i] = NEG;

    // ---- row max ----
    float m = fmaxf(fmaxf(x[0], x[1]), fmaxf(x[2], x[3]));
    redv[tid] = m;
    __syncthreads();
    for (int s = 128; s > 0; s >>= 1) {
        if (tid < s) redv[tid] = fmaxf(redv[tid], redv[tid + s]);
        __syncthreads();
    }
    m = redv[0];
    __syncthreads();

    // ---- sum of exp ----
    float part = 0.0f;
#pragma unroll
    for (int i = 0; i < 4; i++) part += expf(x[i] - m);
    redv[tid] = part;
    __syncthreads();
    for (int s = 128; s > 0; s >>= 1) {
        if (tid < s) redv[tid] += redv[tid + s];
        __syncthreads();
    }
    const float lz = logf(redv[0]);
    __syncthreads();

    // ---- probs write + gumbel-max argmax ----
    float bestv = NEG;
    int besti = 0;
    float* prow = probs_out + (size_t)row * VV;
#pragma unroll
    for (int i = 0; i < 4; i++) {
        int v = tid + i * 256;
        float lp = x[i] - m - lz;            // -inf stays -inf
        prow[v] = expf(lp);
        float uu = urow[v];
        float g = -logf(-logf(uu + 1e-20f) + 1e-20f);
        float sc = lp + g;
        if (sc > bestv) { bestv = sc; besti = v; }   // strict >: earliest v wins
    }
    redv[tid] = bestv;
    redi[tid] = besti;
    __syncthreads();
    for (int s = 128; s > 0; s >>= 1) {
        if (tid < s) {
            float ov = redv[tid + s];
            int   oi = redi[tid + s];
            if (ov > redv[tid] || (ov == redv[tid] && oi < redi[tid])) {
                redv[tid] = ov;
                redi[tid] = oi;
            }
        }
        __syncthreads();
    }
    if (tid == 0) samples[row] = redi[0];
}

// tokens[b*D + d] = (d==0 || samples[0*B+b]==NOTE_TYPE) ? samples[d*B+b] : 0
__global__ __launch_bounds__(256) void tokens_kernel(
    const int* __restrict__ samples, float* __restrict__ tokens_out)
{
    int i = blockIdx.x * 256 + threadIdx.x;  // i over B*D
    if (i >= BB * DD) return;
    int b = i / DD;
    int d = i % DD;
    int s = samples[d * BB + b];
    int type0 = samples[b];                  // samples[0*B + b]
    tokens_out[i] = (d == 0 || type0 == 1) ? (float)s : 0.0f;
}

extern "C" void kernel_launch(void* const* d_in, const int* in_sizes, int n_in,
                              void* d_out, int out_size, void* d_ws, size_t ws_size,
                              hipStream_t stream) {
    const float* logits = (const float*)d_in[0];
    const float* unoise = (const float*)d_in[1];
    const int* curvals = (const int*)d_in[2];

    float* out = (float*)d_out;
    float* tokens_out = out;                       // [B*D]
    float* probs_out = out + (size_t)BB * DD;      // [D*B*V]
    int* samples = (int*)d_ws;                     // [D*B]

    decode_row_kernel<<<DD * BB, 256, 0, stream>>>(logits, unoise, curvals,
                                                   probs_out, samples);
    tokens_kernel<<<(BB * DD + 255) / 256, 256, 0, stream>>>(samples, tokens_out);
}

// Round 2
// 319.804 us; speedup vs baseline: 1.2395x; 1.2395x over previous
//
#include <hip/hip_runtime.h>
#include <math.h>

#define DD 8
#define BB 4096
#define VV 1024
#define K_SEL 102
#define RPB 4            // rows (waves) per block

// order-preserving float <-> uint key maps (bijective, exact)
__device__ __forceinline__ unsigned f2key(float f) {
    unsigned u = __float_as_uint(f);
    unsigned m = (unsigned)((int)u >> 31) | 0x80000000u;  // neg: FFFFFFFF, pos: 80000000
    return u ^ m;
}
__device__ __forceinline__ float key2f(unsigned k) {
    unsigned m = 0x80000000u | ~((unsigned)((int)k >> 31)); // top set: 80000000, else FFFFFFFF
    return __uint_as_float(k ^ m);
}

// One WAVE per (d,b) row: 16 elems/lane, wave-private LDS histogram, no __syncthreads.
__global__ __launch_bounds__(256) void decode_row_kernel(
    const float* __restrict__ logits,
    const float* __restrict__ unoise,
    const int* __restrict__ curvals,
    float* __restrict__ probs_out,   // [D*B*V]
    int* __restrict__ samples)       // [D*B] workspace
{
    const int wave = threadIdx.x >> 6;
    const int lane = threadIdx.x & 63;
    const int row  = blockIdx.x * RPB + wave;

    // 4 replica histograms per wave, replica stride 260 dwords (1040B: 16B-aligned,
    // bank-shifted by 4 per replica so same-digit/different-rep hits different banks).
    __shared__ __align__(16) unsigned hist[RPB][1040];
    unsigned* h = hist[wave];

    const float4* l4 = (const float4*)(logits + (size_t)row * VV);
    const float4* u4 = (const float4*)(unoise + (size_t)row * VV);
    const int cv = curvals[row];

    // ---- load + mask -> order keys ----
    unsigned key[16];
#pragma unroll
    for (int i = 0; i < 4; i++) {
        float4 f = l4[i * 64 + lane];
        const int vb = i * 256 + lane * 4;
        float e[4] = {f.x, f.y, f.z, f.w};
#pragma unroll
        for (int j = 0; j < 4; j++) {
            int v = vb + j;
            float t = (v < cv || v == 0) ? -INFINITY : e[j];
            key[i * 4 + j] = f2key(t);
        }
    }

    // ---- exact radix select (MSB-first, 4x8 bits): key of K_SEL-th largest ----
    unsigned prefix = 0;
    unsigned kk = K_SEL;
    const int rep = (lane & 3) * 260;
#pragma unroll
    for (int pass = 0; pass < 4; pass++) {
        const int shift = 24 - 8 * pass;
        const uint4 z = {0u, 0u, 0u, 0u};
#pragma unroll
        for (int r = 0; r < 4; r++)
            ((uint4*)(h + r * 260))[lane] = z;   // lane clears its 4 owned digits, all reps
        __builtin_amdgcn_wave_barrier();
#pragma unroll
        for (int i = 0; i < 16; i++) {
            bool act = (pass == 0) ||
                       (((key[i] ^ prefix) >> ((shift + 8) & 31)) == 0);
            if (act) atomicAdd(h + rep + ((key[i] >> shift) & 0xFFu), 1u);
        }
        __threadfence_block();                    // order atomics before reads (in-wave)
        __builtin_amdgcn_wave_barrier();
        uint4 c0 = ((uint4*)(h + 0 * 260))[lane];
        uint4 c1 = ((uint4*)(h + 1 * 260))[lane];
        uint4 c2 = ((uint4*)(h + 2 * 260))[lane];
        uint4 c3 = ((uint4*)(h + 3 * 260))[lane];
        __builtin_amdgcn_wave_barrier();
        unsigned cnt0 = c0.x + c1.x + c2.x + c3.x;
        unsigned cnt1 = c0.y + c1.y + c2.y + c3.y;
        unsigned cnt2 = c0.z + c1.z + c2.z + c3.z;
        unsigned cnt3 = c0.w + c1.w + c2.w + c3.w;
        // local suffix sums over lane's 4 digits (digit 4*lane+j)
        unsigned s3 = cnt3;
        unsigned s2 = cnt2 + s3;
        unsigned s1 = cnt1 + s2;
        unsigned s0 = cnt0 + s1;
        // wave inclusive suffix scan of per-lane totals
        unsigned suf = s0;
#pragma unroll
        for (int off = 1; off < 64; off <<= 1) {
            unsigned o = __shfl_down(suf, off, 64);
            suf += (lane + off < 64) ? o : 0u;
        }
        const unsigned above = suf - s0;          // count in digits owned by lanes > lane
        // find the unique digit with gt < kk <= ge
        unsigned sel = 0u;
        bool found = false;
        {
            unsigned ge, gt;
            ge = s0 + above; gt = ge - cnt0;
            if (ge >= kk && gt < kk) { found = true; sel = ((unsigned)(lane * 4 + 0) << 16) | (kk - gt); }
            ge = s1 + above; gt = ge - cnt1;
            if (ge >= kk && gt < kk) { found = true; sel = ((unsigned)(lane * 4 + 1) << 16) | (kk - gt); }
            ge = s2 + above; gt = ge - cnt2;
            if (ge >= kk && gt < kk) { found = true; sel = ((unsigned)(lane * 4 + 2) << 16) | (kk - gt); }
            ge = s3 + above; gt = ge - cnt3;
            if (ge >= kk && gt < kk) { found = true; sel = ((unsigned)(lane * 4 + 3) << 16) | (kk - gt); }
        }
        unsigned long long bal = __ballot(found);
        int src = __ffsll((unsigned long long)bal) - 1;
        sel = __shfl(sel, src, 64);
        prefix |= (sel >> 16) << shift;
        kk = sel & 0xFFFFu;
        __builtin_amdgcn_wave_barrier();
    }
    // prefix == exact key of the 102nd-largest masked logit

    // ---- row max (key space, butterfly) ----
    unsigned mk = key[0];
#pragma unroll
    for (int i = 1; i < 16; i++) mk = max(mk, key[i]);
#pragma unroll
    for (int off = 32; off; off >>= 1)
        mk = max(mk, (unsigned)__shfl_xor(mk, off, 64));
    const float m = key2f(mk);

    // ---- sum of exp over kept elements ----
    float ex[16];
    float s = 0.0f;
#pragma unroll
    for (int i = 0; i < 16; i++) {
        bool keep = key[i] >= prefix;
        float e = keep ? __expf(key2f(key[i]) - m) : 0.0f;
        ex[i] = e;
        s += e;
    }
#pragma unroll
    for (int off = 32; off; off >>= 1)
        s += __shfl_xor(s, off, 64);

    const float lz  = __logf(s);
    const float inv = 1.0f / s;
    const float mlz = m + lz;

    // ---- probs write + gumbel-max argmax ----
    float bestv = -INFINITY;
    int   besti = VV;
    float4* p4 = (float4*)(probs_out + (size_t)row * VV);
#pragma unroll
    for (int i = 0; i < 4; i++) {
        float4 uu = u4[i * 64 + lane];
        float4 pv;
        pv.x = ex[i * 4 + 0] * inv;
        pv.y = ex[i * 4 + 1] * inv;
        pv.z = ex[i * 4 + 2] * inv;
        pv.w = ex[i * 4 + 3] * inv;
        p4[i * 64 + lane] = pv;
        float us[4] = {uu.x, uu.y, uu.z, uu.w};
#pragma unroll
        for (int j = 0; j < 4; j++) {
            const int idx = i * 4 + j;
            bool keep = key[idx] >= prefix;
            float lp = keep ? (key2f(key[idx]) - mlz) : -INFINITY;
            float g = -__logf(-__logf(us[j] + 1e-20f) + 1e-20f);
            float sc = lp + g;
            int v = i * 256 + lane * 4 + j;
            if (sc > bestv) { bestv = sc; besti = v; }   // strict >: earliest v in-lane
        }
    }
#pragma unroll
    for (int off = 32; off; off >>= 1) {
        float ov = __shfl_xor(bestv, off, 64);
        int   oi = __shfl_xor(besti, off, 64);
        if (ov > bestv || (ov == bestv && oi < besti)) { bestv = ov; besti = oi; }
    }
    if (lane == 0) samples[row] = besti;
}

// tokens[b*D + d] = (d==0 || samples[b]==NOTE_TYPE) ? samples[d*B+b] : 0
__global__ __launch_bounds__(256) void tokens_kernel(
    const int* __restrict__ samples, float* __restrict__ tokens_out)
{
    int i = blockIdx.x * 256 + threadIdx.x;   // exactly B*D threads
    int b = i >> 3;
    int d = i & 7;
    int sm = samples[d * BB + b];
    int t0 = samples[b];
    tokens_out[i] = (d == 0 || t0 == 1) ? (float)sm : 0.0f;
}

extern "C" void kernel_launch(void* const* d_in, const int* in_sizes, int n_in,
                              void* d_out, int out_size, void* d_ws, size_t ws_size,
                              hipStream_t stream) {
    const float* logits = (const float*)d_in[0];
    const float* unoise = (const float*)d_in[1];
    const int*   curvals = (const int*)d_in[2];

    float* out        = (float*)d_out;
    float* tokens_out = out;                       // [B*D]
    float* probs_out  = out + (size_t)BB * DD;     // [D*B*V]
    int*   samples    = (int*)d_ws;                // [D*B]

    decode_row_kernel<<<(DD * BB) / RPB, 256, 0, stream>>>(logits, unoise, curvals,
                                                           probs_out, samples);
    tokens_kernel<<<(BB * DD) / 256, 256, 0, stream>>>(samples, tokens_out);
}